// Round 1
// baseline (801.023 us; speedup 1.0000x reference)
//
#include <hip/hip_runtime.h>
#include <math.h>

// Segmented sum over 8.4M rows into 8192 segments + log-sigmoid epilogue.
// out[b*2+0] = log(sigmoid(10*(1 - sum(l1+l2))) + 1e-10)
// out[b*2+1] = log(sigmoid(10*(5 - sum(l0)))    + 1e-10)

constexpr float KSHARP = 10.0f;
constexpr float EPS    = 1e-10f;

__device__ __forceinline__ float stable_sigmoid(float x) {
    // matches jax.nn.sigmoid (stable two-branch form)
    if (x >= 0.0f) {
        return 1.0f / (1.0f + __expf(-x) * 0.0f + expf(-x) * 1.0f); // keep precise expf
    } else {
        float e = expf(x);
        return e / (1.0f + e);
    }
}

__global__ void accum_kernel(const float* __restrict__ logits,
                             const int* __restrict__ idx,
                             float* __restrict__ sums,   // sums[2*b]=s1, sums[2*b+1]=s0
                             int n) {
    int tid    = blockIdx.x * blockDim.x + threadIdx.x;
    int stride = gridDim.x * blockDim.x;
    for (long long e = (long long)tid * 4; e < n; e += (long long)stride * 4) {
        int rem = n - (int)e;
        if (rem >= 4) {
            // 4 rows = 12 floats = 3 float4 loads (16B-aligned since e%4==0)
            const float4* p = (const float4*)(logits + 3 * e);
            float4 a = p[0], b = p[1], c = p[2];
            int4 id = *(const int4*)(idx + e);
            // row 0: a.x a.y a.z | row 1: a.w b.x b.y | row 2: b.z b.w c.x | row 3: c.y c.z c.w
            atomicAdd(&sums[2 * id.x],     a.y + a.z);
            atomicAdd(&sums[2 * id.x + 1], a.x);
            atomicAdd(&sums[2 * id.y],     b.x + b.y);
            atomicAdd(&sums[2 * id.y + 1], a.w);
            atomicAdd(&sums[2 * id.z],     b.w + c.x);
            atomicAdd(&sums[2 * id.z + 1], b.z);
            atomicAdd(&sums[2 * id.w],     c.z + c.w);
            atomicAdd(&sums[2 * id.w + 1], c.y);
        } else {
            for (int r = 0; r < rem; ++r) {
                long long row = e + r;
                float l0 = logits[3 * row + 0];
                float l1 = logits[3 * row + 1];
                float l2 = logits[3 * row + 2];
                int b = idx[row];
                atomicAdd(&sums[2 * b],     l1 + l2);
                atomicAdd(&sums[2 * b + 1], l0);
            }
        }
    }
}

__global__ void finalize_kernel(const float* __restrict__ sums,
                                float* __restrict__ out,
                                int batch) {
    int b = blockIdx.x * blockDim.x + threadIdx.x;
    if (b >= batch) return;
    float s1 = sums[2 * b];
    float s0 = sums[2 * b + 1];
    float x1 = KSHARP * (1.0f - s1);
    float x0 = KSHARP * (5.0f - s0);
    // stable sigmoid, then +eps, log
    float sig1, sig0;
    {
        float x = x1;
        sig1 = (x >= 0.0f) ? (1.0f / (1.0f + expf(-x)))
                           : ({ float ex = expf(x); ex / (1.0f + ex); });
    }
    {
        float x = x0;
        sig0 = (x >= 0.0f) ? (1.0f / (1.0f + expf(-x)))
                           : ({ float ex = expf(x); ex / (1.0f + ex); });
    }
    out[2 * b + 0] = logf(sig1 + EPS);
    out[2 * b + 1] = logf(sig0 + EPS);
}

extern "C" void kernel_launch(void* const* d_in, const int* in_sizes, int n_in,
                              void* d_out, int out_size, void* d_ws, size_t ws_size,
                              hipStream_t stream) {
    const float* logits = (const float*)d_in[0];
    const int*   idx    = (const int*)d_in[1];
    int n     = in_sizes[1];          // number of rows (8388608)
    int batch = out_size / 2;         // 8192

    float* sums = (float*)d_ws;       // 2*batch floats

    hipMemsetAsync(sums, 0, (size_t)2 * batch * sizeof(float), stream);

    const int threads = 256;
    int work = (n + 3) / 4;
    int blocks = (work + threads - 1) / threads;
    if (blocks > 2048) blocks = 2048;
    accum_kernel<<<blocks, threads, 0, stream>>>(logits, idx, sums, n);

    int fblocks = (batch + threads - 1) / threads;
    finalize_kernel<<<fblocks, threads, 0, stream>>>(sums, out_size ? (float*)d_out : nullptr, batch);
}

// Round 2
// 126.827 us; speedup vs baseline: 6.3159x; 6.3159x over previous
//
#include <hip/hip_runtime.h>
#include <math.h>

// Segmented sum over n rows into `batch` segments + log-sigmoid epilogue.
// out[2*b+0] = log(sigmoid(10*(1 - sum(l1+l2))) + 1e-10)
// out[2*b+1] = log(sigmoid(10*(5 - sum(l0)))    + 1e-10)
//
// Strategy: per-block LDS privatized accumulators (no global atomics,
// bit-deterministic), per-block partials to d_ws, then tree-reduce + epilogue.

constexpr float KSHARP = 10.0f;
constexpr float EPS    = 1e-10f;
constexpr int   MAXSEG = 8192;
constexpr int   S2     = 2 * MAXSEG;   // 16384 floats = 64 KiB LDS / block

__global__ __launch_bounds__(512) void seg_partial_kernel(
    const float* __restrict__ logits, const int* __restrict__ idx,
    float* __restrict__ partials, int n, int chunk)
{
    __shared__ float lds[S2];
    for (int i = threadIdx.x; i < S2; i += blockDim.x) lds[i] = 0.0f;
    __syncthreads();

    long long cs = (long long)blockIdx.x * chunk;
    long long ce = cs + chunk; if (ce > n) ce = n;
    if (cs < ce) {
        int rows = (int)(ce - cs);
        int ngr  = rows >> 2;                 // full groups of 4 rows
        for (int g = threadIdx.x; g < ngr; g += blockDim.x) {
            long long r = cs + ((long long)g << 2);
            const float4* p = (const float4*)(logits + 3 * r);
            float4 a = p[0], b = p[1], c = p[2];
            int4 id = *(const int4*)(idx + r);
            // row0: a.x a.y a.z | row1: a.w b.x b.y | row2: b.z b.w c.x | row3: c.y c.z c.w
            atomicAdd(&lds[2 * id.x],     a.y + a.z);
            atomicAdd(&lds[2 * id.x + 1], a.x);
            atomicAdd(&lds[2 * id.y],     b.x + b.y);
            atomicAdd(&lds[2 * id.y + 1], a.w);
            atomicAdd(&lds[2 * id.z],     b.w + c.x);
            atomicAdd(&lds[2 * id.z + 1], b.z);
            atomicAdd(&lds[2 * id.w],     c.z + c.w);
            atomicAdd(&lds[2 * id.w + 1], c.y);
        }
        int tail = rows & 3;
        if ((int)threadIdx.x < tail) {
            long long r = cs + ((long long)ngr << 2) + threadIdx.x;
            float l0 = logits[3 * r], l1 = logits[3 * r + 1], l2 = logits[3 * r + 2];
            int b = idx[r];
            atomicAdd(&lds[2 * b],     l1 + l2);
            atomicAdd(&lds[2 * b + 1], l0);
        }
    }
    __syncthreads();
    float* dst = partials + (size_t)blockIdx.x * S2;
    for (int i = threadIdx.x; i < S2; i += blockDim.x) dst[i] = lds[i];
}

__global__ __launch_bounds__(1024) void reduce_finalize_kernel(
    const float* __restrict__ partials, float* __restrict__ out,
    int nb, int total /* = 2*batch */)
{
    // blockDim = (256, 4): x = output index within block, y = partial-range split
    int j = blockIdx.x * 256 + threadIdx.x;
    float s = 0.0f;
    if (j < total) {
        for (int b = threadIdx.y; b < nb; b += 4)
            s += partials[(size_t)b * S2 + j];
    }
    __shared__ float red[4][256];
    red[threadIdx.y][threadIdx.x] = s;
    __syncthreads();
    if (threadIdx.y == 0 && j < total) {
        s = red[0][threadIdx.x] + red[1][threadIdx.x]
          + red[2][threadIdx.x] + red[3][threadIdx.x];
        float C = (j & 1) ? 5.0f : 1.0f;
        float x = KSHARP * (C - s);
        float sig;
        if (x >= 0.0f) { sig = 1.0f / (1.0f + expf(-x)); }
        else           { float e = expf(x); sig = e / (1.0f + e); }
        out[j] = logf(sig + EPS);
    }
}

// ---- fallback path (tiny ws or batch > 8192): global atomics ----
__global__ void accum_atomic_kernel(const float* __restrict__ logits,
                                    const int* __restrict__ idx,
                                    float* __restrict__ sums, int n)
{
    int tid = blockIdx.x * blockDim.x + threadIdx.x;
    int stride = gridDim.x * blockDim.x;
    for (long long r = tid; r < n; r += stride) {
        float l0 = logits[3 * r], l1 = logits[3 * r + 1], l2 = logits[3 * r + 2];
        int b = idx[r];
        atomicAdd(&sums[2 * b],     l1 + l2);
        atomicAdd(&sums[2 * b + 1], l0);
    }
}

__global__ void finalize_kernel(const float* __restrict__ sums,
                                float* __restrict__ out, int total)
{
    int j = blockIdx.x * blockDim.x + threadIdx.x;
    if (j >= total) return;
    float s = sums[j];
    float C = (j & 1) ? 5.0f : 1.0f;
    float x = KSHARP * (C - s);
    float sig;
    if (x >= 0.0f) { sig = 1.0f / (1.0f + expf(-x)); }
    else           { float e = expf(x); sig = e / (1.0f + e); }
    out[j] = logf(sig + EPS);
}

extern "C" void kernel_launch(void* const* d_in, const int* in_sizes, int n_in,
                              void* d_out, int out_size, void* d_ws, size_t ws_size,
                              hipStream_t stream) {
    const float* logits = (const float*)d_in[0];
    const int*   idx    = (const int*)d_in[1];
    int n     = in_sizes[1];       // rows (8388608)
    int batch = out_size / 2;      // 8192
    float* out = (float*)d_out;

    size_t bytes_per_block = (size_t)S2 * sizeof(float);   // 64 KiB
    int nb_max = (int)(ws_size / bytes_per_block);
    int nb = nb_max < 512 ? nb_max : 512;

    if (batch <= MAXSEG && nb >= 8) {
        // chunk: rows per block, multiple of 4
        long long chunk_ll = ((long long)n + nb - 1) / nb;
        int chunk = (int)((chunk_ll + 3) & ~3LL);
        float* partials = (float*)d_ws;
        seg_partial_kernel<<<nb, 512, 0, stream>>>(logits, idx, partials, n, chunk);

        int total = 2 * batch;
        dim3 rb(256, 4);
        int rblocks = (total + 255) / 256;
        reduce_finalize_kernel<<<rblocks, rb, 0, stream>>>(partials, out, nb, total);
    } else {
        // fallback: global-atomic path
        float* sums = (float*)d_ws;
        hipMemsetAsync(sums, 0, (size_t)2 * batch * sizeof(float), stream);
        int threads = 256;
        int blocks = (n + threads - 1) / threads;
        if (blocks > 2048) blocks = 2048;
        accum_atomic_kernel<<<blocks, threads, 0, stream>>>(logits, idx, sums, n);
        int total = 2 * batch;
        finalize_kernel<<<(total + 255) / 256, 256, 0, stream>>>(sums, out, total);
    }
}

// Round 3
// 103.191 us; speedup vs baseline: 7.7625x; 1.2290x over previous
//
#include <hip/hip_runtime.h>
#include <math.h>

// Segmented sum over n rows into `batch` (<=8192) segments + log-sigmoid epilogue.
// out[2*b+0] = log(sigmoid(10*(1 - sum(l1+l2))) + 1e-10)
// out[2*b+1] = log(sigmoid(10*(5 - sum(l0)))    + 1e-10)
//
// Per-block LDS privatized accumulators in SoA layout (full 32-bank spread for
// the random-index atomics), partials to d_ws, deterministic tree-reduce + epilogue.

constexpr float KSHARP = 10.0f;
constexpr float EPS    = 1e-10f;
constexpr int   SEG    = 8192;
constexpr int   S2     = 2 * SEG;      // 16384 floats = 64 KiB LDS / block

__global__ __launch_bounds__(1024, 8) void seg_partial_kernel(
    const float* __restrict__ logits, const int* __restrict__ idx,
    float* __restrict__ partials, int n, int chunk)
{
    __shared__ float s1[SEG];
    __shared__ float s0[SEG];
    {
        float4 z = make_float4(0.f, 0.f, 0.f, 0.f);
        float4* p1 = (float4*)s1; float4* p0 = (float4*)s0;
        for (int i = threadIdx.x; i < SEG / 4; i += blockDim.x) { p1[i] = z; p0[i] = z; }
    }
    __syncthreads();

    long long cs = (long long)blockIdx.x * chunk;
    long long ce = cs + chunk; if (ce > n) ce = n;
    if (cs < ce) {
        int rows = (int)(ce - cs);
        int ngr  = rows >> 2;                  // groups of 4 rows
        for (int g = threadIdx.x; g < ngr; g += blockDim.x) {
            long long r = cs + ((long long)g << 2);
            const float4* p = (const float4*)(logits + 3 * r);
            float4 a = p[0], b = p[1], c = p[2];
            int4 id = *(const int4*)(idx + r);
            // row0: a.x a.y a.z | row1: a.w b.x b.y | row2: b.z b.w c.x | row3: c.y c.z c.w
            atomicAdd(&s1[id.x], a.y + a.z);
            atomicAdd(&s0[id.x], a.x);
            atomicAdd(&s1[id.y], b.x + b.y);
            atomicAdd(&s0[id.y], a.w);
            atomicAdd(&s1[id.z], b.w + c.x);
            atomicAdd(&s0[id.z], b.z);
            atomicAdd(&s1[id.w], c.z + c.w);
            atomicAdd(&s0[id.w], c.y);
        }
        int tail = rows & 3;
        if ((int)threadIdx.x < tail) {
            long long r = cs + ((long long)ngr << 2) + threadIdx.x;
            float l0 = logits[3 * r], l1 = logits[3 * r + 1], l2 = logits[3 * r + 2];
            int b = idx[r];
            atomicAdd(&s1[b], l1 + l2);
            atomicAdd(&s0[b], l0);
        }
    }
    __syncthreads();
    // partials layout per block: [0..SEG) = s1, [SEG..2*SEG) = s0
    float4* dst = (float4*)(partials + (size_t)blockIdx.x * S2);
    const float4* p1 = (const float4*)s1;
    const float4* p0 = (const float4*)s0;
    for (int i = threadIdx.x; i < SEG / 4; i += blockDim.x) dst[i] = p1[i];
    for (int i = threadIdx.x; i < SEG / 4; i += blockDim.x) dst[SEG / 4 + i] = p0[i];
}

__global__ __launch_bounds__(1024) void reduce_finalize_kernel(
    const float* __restrict__ partials, float* __restrict__ out,
    int nb, int batch)
{
    // blockDim = (64, 16); j indexes the 2*SEG partial columns
    int j = blockIdx.x * 64 + threadIdx.x;
    float s = 0.0f;
    for (int b = threadIdx.y; b < nb; b += 16)
        s += partials[(size_t)b * S2 + j];
    __shared__ float red[16][64];
    red[threadIdx.y][threadIdx.x] = s;
    __syncthreads();
    if (threadIdx.y == 0) {
        s = 0.0f;
        #pragma unroll
        for (int y = 0; y < 16; ++y) s += red[y][threadIdx.x];
        bool is_s1 = (j < SEG);
        int  b     = is_s1 ? j : j - SEG;
        if (b < batch) {
            float C = is_s1 ? 1.0f : 5.0f;
            float x = KSHARP * (C - s);
            float sig;
            if (x >= 0.0f) { sig = 1.0f / (1.0f + expf(-x)); }
            else           { float e = expf(x); sig = e / (1.0f + e); }
            out[2 * b + (is_s1 ? 0 : 1)] = logf(sig + EPS);
        }
    }
}

// ---- fallback path (tiny ws or batch > 8192): global atomics ----
__global__ void accum_atomic_kernel(const float* __restrict__ logits,
                                    const int* __restrict__ idx,
                                    float* __restrict__ sums, int n)
{
    int tid = blockIdx.x * blockDim.x + threadIdx.x;
    int stride = gridDim.x * blockDim.x;
    for (long long r = tid; r < n; r += stride) {
        float l0 = logits[3 * r], l1 = logits[3 * r + 1], l2 = logits[3 * r + 2];
        int b = idx[r];
        atomicAdd(&sums[2 * b],     l1 + l2);
        atomicAdd(&sums[2 * b + 1], l0);
    }
}

__global__ void finalize_kernel(const float* __restrict__ sums,
                                float* __restrict__ out, int total)
{
    int j = blockIdx.x * blockDim.x + threadIdx.x;
    if (j >= total) return;
    float s = sums[j];
    float C = (j & 1) ? 5.0f : 1.0f;
    float x = KSHARP * (C - s);
    float sig;
    if (x >= 0.0f) { sig = 1.0f / (1.0f + expf(-x)); }
    else           { float e = expf(x); sig = e / (1.0f + e); }
    out[j] = logf(sig + EPS);
}

extern "C" void kernel_launch(void* const* d_in, const int* in_sizes, int n_in,
                              void* d_out, int out_size, void* d_ws, size_t ws_size,
                              hipStream_t stream) {
    const float* logits = (const float*)d_in[0];
    const int*   idx    = (const int*)d_in[1];
    int n     = in_sizes[1];       // rows (8388608)
    int batch = out_size / 2;      // 8192
    float* out = (float*)d_out;

    size_t bytes_per_block = (size_t)S2 * sizeof(float);   // 64 KiB
    int nb_max = (int)(ws_size / bytes_per_block);
    int nb = nb_max < 512 ? nb_max : 512;

    if (batch <= SEG && nb >= 8) {
        long long chunk_ll = ((long long)n + nb - 1) / nb;
        int chunk = (int)((chunk_ll + 3) & ~3LL);          // multiple of 4
        float* partials = (float*)d_ws;
        seg_partial_kernel<<<nb, 1024, 0, stream>>>(logits, idx, partials, n, chunk);

        dim3 rb(64, 16);
        reduce_finalize_kernel<<<S2 / 64, rb, 0, stream>>>(partials, out, nb, batch);
    } else {
        float* sums = (float*)d_ws;
        hipMemsetAsync(sums, 0, (size_t)2 * batch * sizeof(float), stream);
        int threads = 256;
        int blocks = (n + threads - 1) / threads;
        if (blocks > 2048) blocks = 2048;
        accum_atomic_kernel<<<blocks, threads, 0, stream>>>(logits, idx, sums, n);
        int total = 2 * batch;
        finalize_kernel<<<(total + 255) / 256, 256, 0, stream>>>(sums, out, total);
    }
}

// Round 5
// 43.761 us; speedup vs baseline: 18.3047x; 2.3581x over previous
//
#include <hip/hip_runtime.h>
#include <math.h>

// Segmented sum over n rows into `batch` (<=8192) segments + log-sigmoid epilogue.
// out[2*b+0] = log(sigmoid(10*(1 - sum(l1+l2))) + 1e-10)
// out[2*b+1] = log(sigmoid(10*(5 - sum(l0)))    + 1e-10)
//
// Per-block LDS privatized accumulators in FIXED-POINT int32 (atomicAdd(int*)
// on LDS always lowers to the HW ds_add_u32 instruction — float atomicAdd gets
// CAS-expanded, which was the 90us bottleneck in earlier rounds).
// Scale 2^21: quantization error ~2e-7/add * ~1024 adds * slope 10 << 0.46 thr.
// Integer adds are associative -> bit-deterministic. Partials to d_ws,
// tree-reduce in int64 + epilogue.

constexpr float KSHARP   = 10.0f;
constexpr float EPS      = 1e-10f;
constexpr int   SEG      = 8192;
constexpr int   S2       = 2 * SEG;            // 16384 ints = 64 KiB LDS / block
constexpr float SCALE    = 2097152.0f;         // 2^21
constexpr float INV_SCALE = 1.0f / 2097152.0f;

__global__ __launch_bounds__(1024, 8) void seg_partial_kernel(
    const float* __restrict__ logits, const int* __restrict__ idx,
    int* __restrict__ partials, int n, int chunk)
{
    __shared__ int s1[SEG];
    __shared__ int s0[SEG];
    {
        int4 z = make_int4(0, 0, 0, 0);
        int4* p1 = (int4*)s1; int4* p0 = (int4*)s0;
        for (int i = threadIdx.x; i < SEG / 4; i += blockDim.x) { p1[i] = z; p0[i] = z; }
    }
    __syncthreads();

    long long cs = (long long)blockIdx.x * chunk;
    long long ce = cs + chunk; if (ce > n) ce = n;
    if (cs < ce) {
        int rows = (int)(ce - cs);
        int ngr  = rows >> 2;                  // groups of 4 rows
        for (int g = threadIdx.x; g < ngr; g += blockDim.x) {
            long long r = cs + ((long long)g << 2);
            const float4* p = (const float4*)(logits + 3 * r);
            float4 a = p[0], b = p[1], c = p[2];
            int4 id = *(const int4*)(idx + r);
            // row0: a.x a.y a.z | row1: a.w b.x b.y | row2: b.z b.w c.x | row3: c.y c.z c.w
            atomicAdd(&s1[id.x], __float2int_rn((a.y + a.z) * SCALE));
            atomicAdd(&s0[id.x], __float2int_rn(a.x * SCALE));
            atomicAdd(&s1[id.y], __float2int_rn((b.x + b.y) * SCALE));
            atomicAdd(&s0[id.y], __float2int_rn(a.w * SCALE));
            atomicAdd(&s1[id.z], __float2int_rn((b.w + c.x) * SCALE));
            atomicAdd(&s0[id.z], __float2int_rn(b.z * SCALE));
            atomicAdd(&s1[id.w], __float2int_rn((c.z + c.w) * SCALE));
            atomicAdd(&s0[id.w], __float2int_rn(c.y * SCALE));
        }
        int tail = rows & 3;
        if ((int)threadIdx.x < tail) {
            long long r = cs + ((long long)ngr << 2) + threadIdx.x;
            float l0 = logits[3 * r], l1 = logits[3 * r + 1], l2 = logits[3 * r + 2];
            int b = idx[r];
            atomicAdd(&s1[b], __float2int_rn((l1 + l2) * SCALE));
            atomicAdd(&s0[b], __float2int_rn(l0 * SCALE));
        }
    }
    __syncthreads();
    // partials layout per block: [0..SEG) = s1, [SEG..2*SEG) = s0
    int4* dst = (int4*)(partials + (size_t)blockIdx.x * S2);
    const int4* p1 = (const int4*)s1;
    const int4* p0 = (const int4*)s0;
    for (int i = threadIdx.x; i < SEG / 4; i += blockDim.x) dst[i] = p1[i];
    for (int i = threadIdx.x; i < SEG / 4; i += blockDim.x) dst[SEG / 4 + i] = p0[i];
}

__global__ __launch_bounds__(1024) void reduce_finalize_kernel(
    const int* __restrict__ partials, float* __restrict__ out,
    int nb, int batch)
{
    // blockDim = (64,16). Each thread owns 4 consecutive columns (int4 loads).
    // grid: S2/256 blocks, each block covers 256 columns of the 2*SEG space.
    int col4 = blockIdx.x * 64 + threadIdx.x;          // unit of 4 columns
    const int4* p4 = (const int4*)partials;
    long long a0 = 0, a1 = 0, a2 = 0, a3 = 0;
    for (int b = threadIdx.y; b < nb; b += 16) {
        int4 v = p4[(size_t)b * (S2 / 4) + col4];
        a0 += v.x; a1 += v.y; a2 += v.z; a3 += v.w;
    }
    __shared__ long long red[16][64][4];
    red[threadIdx.y][threadIdx.x][0] = a0;
    red[threadIdx.y][threadIdx.x][1] = a1;
    red[threadIdx.y][threadIdx.x][2] = a2;
    red[threadIdx.y][threadIdx.x][3] = a3;
    __syncthreads();
    if (threadIdx.y == 0) {
        long long t0 = 0, t1 = 0, t2 = 0, t3 = 0;
        #pragma unroll
        for (int y = 0; y < 16; ++y) {
            t0 += red[y][threadIdx.x][0];
            t1 += red[y][threadIdx.x][1];
            t2 += red[y][threadIdx.x][2];
            t3 += red[y][threadIdx.x][3];
        }
        long long tot[4] = {t0, t1, t2, t3};
        #pragma unroll
        for (int q = 0; q < 4; ++q) {
            int j = col4 * 4 + q;
            float s = (float)tot[q] * INV_SCALE;
            bool is_s1 = (j < SEG);
            int  b     = is_s1 ? j : j - SEG;
            if (b < batch) {
                float C = is_s1 ? 1.0f : 5.0f;
                float x = KSHARP * (C - s);
                float sig;
                if (x >= 0.0f) { sig = 1.0f / (1.0f + expf(-x)); }
                else           { float e = expf(x); sig = e / (1.0f + e); }
                out[2 * b + (is_s1 ? 0 : 1)] = logf(sig + EPS);
            }
        }
    }
}

// ---- fallback path (tiny ws or batch > 8192): global float atomics ----
__global__ void accum_atomic_kernel(const float* __restrict__ logits,
                                    const int* __restrict__ idx,
                                    float* __restrict__ sums, int n)
{
    int tid = blockIdx.x * blockDim.x + threadIdx.x;
    int stride = gridDim.x * blockDim.x;
    for (long long r = tid; r < n; r += stride) {
        float l0 = logits[3 * r], l1 = logits[3 * r + 1], l2 = logits[3 * r + 2];
        int b = idx[r];
        atomicAdd(&sums[2 * b],     l1 + l2);
        atomicAdd(&sums[2 * b + 1], l0);
    }
}

__global__ void finalize_kernel(const float* __restrict__ sums,
                                float* __restrict__ out, int total)
{
    int j = blockIdx.x * blockDim.x + threadIdx.x;
    if (j >= total) return;
    float s = sums[j];
    float C = (j & 1) ? 5.0f : 1.0f;
    float x = KSHARP * (C - s);
    float sig;
    if (x >= 0.0f) { sig = 1.0f / (1.0f + expf(-x)); }
    else           { float e = expf(x); sig = e / (1.0f + e); }
    out[j] = logf(sig + EPS);
}

extern "C" void kernel_launch(void* const* d_in, const int* in_sizes, int n_in,
                              void* d_out, int out_size, void* d_ws, size_t ws_size,
                              hipStream_t stream) {
    const float* logits = (const float*)d_in[0];
    const int*   idx    = (const int*)d_in[1];
    int n     = in_sizes[1];       // rows (8388608)
    int batch = out_size / 2;      // 8192
    float* out = (float*)d_out;

    size_t bytes_per_block = (size_t)S2 * sizeof(int);   // 64 KiB
    int nb_max = (int)(ws_size / bytes_per_block);
    int nb = nb_max < 512 ? nb_max : 512;

    if (batch <= SEG && nb >= 8) {
        long long chunk_ll = ((long long)n + nb - 1) / nb;
        int chunk = (int)((chunk_ll + 3) & ~3LL);          // multiple of 4
        int* partials = (int*)d_ws;
        seg_partial_kernel<<<nb, 1024, 0, stream>>>(logits, idx, partials, n, chunk);

        dim3 rb(64, 16);
        reduce_finalize_kernel<<<S2 / 256, rb, 0, stream>>>(partials, out, nb, batch);
    } else {
        float* sums = (float*)d_ws;
        hipMemsetAsync(sums, 0, (size_t)2 * batch * sizeof(float), stream);
        int threads = 256;
        int blocks = (n + threads - 1) / threads;
        if (blocks > 2048) blocks = 2048;
        accum_atomic_kernel<<<blocks, threads, 0, stream>>>(logits, idx, sums, n);
        int total = 2 * batch;
        finalize_kernel<<<(total + 255) / 256, 256, 0, stream>>>(sums, out, total);
    }
}